// Round 11
// baseline (419.053 us; speedup 1.0000x reference)
//
#include <hip/hip_runtime.h>

#define BATCH 8192
#define LOSC  2048.0f
#define LOINV (1.0f / 2048.0f)

typedef _Float16 f16x4 __attribute__((ext_vector_type(4)));
typedef __fp16   fp16x2 __attribute__((ext_vector_type(2)));
typedef float    f32x4 __attribute__((ext_vector_type(4)));

union PK2 { fp16x2 h; unsigned u; };
union U4  { f16x4 v; unsigned u[2]; };

__device__ __forceinline__ unsigned pkrtz(float a, float b) {
    PK2 p; p.h = __builtin_amdgcn_cvt_pkrtz(a, b); return p.u;
}
__device__ __forceinline__ float lo0(unsigned hp, float v) {
    PK2 p; p.u = hp; return (v - (float)p.h[0]) * LOSC;
}
__device__ __forceinline__ float lo1(unsigned hp, float v) {
    PK2 p; p.u = hp; return (v - (float)p.h[1]) * LOSC;
}

// ---------------------------------------------------------------------------
// Kernel 1: exact NN (CD=1). sqrt(fl(dx*dx)) == |dx| in fp32 -> fabsf;
// first-index argmin (strict < over ascending j), self excluded. ~5 us.
// ---------------------------------------------------------------------------
__global__ __launch_bounds__(256) void nn_kernel(const float* __restrict__ c,
                                                 float* __restrict__ c0) {
    __shared__ float cs[BATCH];
    const int t = threadIdx.x;
    {
        const float4* cg = (const float4*)c;
        float4* cl = (float4*)cs;
        for (int j = t; j < BATCH / 4; j += 256) cl[j] = cg[j];
    }
    __syncthreads();
    const int part = t & 31;
    const int i    = blockIdx.x * 8 + (t >> 5);
    const float ci = cs[i];
    const int sj0 = ((i & 3) == 0) ? (i >> 2) : -1;
    const int sj1 = ((i & 3) == 1) ? (i >> 2) : -1;
    const int sj2 = ((i & 3) == 2) ? (i >> 2) : -1;
    const int sj3 = ((i & 3) == 3) ? (i >> 2) : -1;
    const float4* cs4 = (const float4*)cs;
    float bd0 = 3e38f, bd1 = 3e38f, bd2 = 3e38f, bd3 = 3e38f;
    int   bj0 = 0,     bj1 = 0,     bj2 = 0,     bj3 = 0;
    #pragma unroll 4
    for (int tt = 0; tt < 64; ++tt) {
        const int jj = part + (tt << 5);
        const float4 v = cs4[jj];
        float d0 = fabsf(ci - v.x);
        float d1 = fabsf(ci - v.y);
        float d2 = fabsf(ci - v.z);
        float d3 = fabsf(ci - v.w);
        if (jj == sj0) d0 = 3e38f;
        if (jj == sj1) d1 = 3e38f;
        if (jj == sj2) d2 = 3e38f;
        if (jj == sj3) d3 = 3e38f;
        if (d0 < bd0) { bd0 = d0; bj0 = jj; }
        if (d1 < bd1) { bd1 = d1; bj1 = jj; }
        if (d2 < bd2) { bd2 = d2; bj2 = jj; }
        if (d3 < bd3) { bd3 = d3; bj3 = jj; }
    }
    float best = bd0; int bestj = bj0 * 4 + 0;
    { const int j1 = bj1 * 4 + 1; if (bd1 < best || (bd1 == best && j1 < bestj)) { best = bd1; bestj = j1; } }
    { const int j2 = bj2 * 4 + 2; if (bd2 < best || (bd2 == best && j2 < bestj)) { best = bd2; bestj = j2; } }
    { const int j3 = bj3 * 4 + 3; if (bd3 < best || (bd3 == best && j3 < bestj)) { best = bd3; bestj = j3; } }
    #pragma unroll
    for (int off = 1; off < 32; off <<= 1) {
        const float od = __shfl_xor(best, off);
        const int   oj = __shfl_xor(bestj, off);
        if (od < best || (od == best && oj < bestj)) { best = od; bestj = oj; }
    }
    if (part == 0) c0[i] = cs[bestj];
}

// ---------------------------------------------------------------------------
// Kernel 2 (v11): 2-wave cooperative K-split. Block = 128 thr (2 waves),
// both waves own the SAME 8 samples; wave w handles K-rows [32w,32w+32) of
// the 64x64 GEMMs (K-chunks m_g = 2w+m, m=0..1). Each wave computes partial
// C for all 4 M-tiles; partials for the other wave's tiles are exchanged via
// LDS (disjoint tile indices -> one buffer), 3 barriers/step. B-rebuild per
// wave touches only its own 2 tiles == its own K-rows, so the K=16 identity
// (B k-map q*4+j == C/D row map q*4+r) still gives a zero-shfl transform.
// g combined via LDS in fixed order -> y bitwise-uniform in both waves.
// 2048 waves = 2/SIMD: real-work occupancy, no duplication (R6 lesson).
// ---------------------------------------------------------------------------
__global__ __launch_bounds__(128, 2) void solve_kernel(
    const float* __restrict__ x, const float* __restrict__ c0g,
    const float* __restrict__ W1, const float* __restrict__ b1,
    const float* __restrict__ W2, const float* __restrict__ b2,
    const float* __restrict__ W3, const float* __restrict__ b3,
    const float* __restrict__ W4, float* __restrict__ out)
{
    __shared__ __align__(16) float pbuf2[4][64][4];   // 4 KB, per-tile partials
    __shared__ __align__(16) float pbuf3[4][64][4];   // 4 KB
    __shared__ float gbuf[2][16];

    const int tid  = threadIdx.x;
    const int w    = tid >> 6;            // wave id 0/1
    const int lane = tid & 63;
    const int q  = lane >> 4;
    const int cc = lane & 15;
    const bool fwd = (cc < 8);
    const int s = cc & 7;
    const int sbase = blockIdx.x * 8;

    // ---- weight fragments for OWN K-chunks m_g = 2w+m ----
    f16x4 W2h[4][2], W2l[4][2], W3h[4][2], W3l[4][2];
    #pragma unroll
    for (int T = 0; T < 4; ++T)
        #pragma unroll
        for (int m = 0; m < 2; ++m) {
            const int off = (T * 16 + cc) * 64 + (w * 2 + m) * 16 + q * 4;
            const float4 w2 = *(const float4*)(W2 + off);
            const float4 w3 = *(const float4*)(W3 + off);
            U4 h, l;
            h.u[0] = pkrtz(w2.x, w2.y); h.u[1] = pkrtz(w2.z, w2.w);
            l.u[0] = pkrtz(lo0(h.u[0], w2.x), lo1(h.u[0], w2.y));
            l.u[1] = pkrtz(lo0(h.u[1], w2.z), lo1(h.u[1], w2.w));
            W2h[T][m] = h.v; W2l[T][m] = l.v;
            h.u[0] = pkrtz(w3.x, w3.y); h.u[1] = pkrtz(w3.z, w3.w);
            l.u[0] = pkrtz(lo0(h.u[0], w3.x), lo1(h.u[0], w3.y));
            l.u[1] = pkrtz(lo0(h.u[1], w3.z), lo1(h.u[1], w3.w));
            W3h[T][m] = h.v; W3l[T][m] = l.v;
        }

    // ---- biases (pre-masked) + W4 for OWN tiles' rows (2w+i)*16+q*4+r ----
    float b2m[8], b3m[8], w4r[8];
    #pragma unroll
    for (int i = 0; i < 2; ++i)
        #pragma unroll
        for (int r = 0; r < 4; ++r) {
            const int row = (2 * w + i) * 16 + q * 4 + r;
            b2m[i * 4 + r] = fwd ? b2[row] : 0.f;
            b3m[i * 4 + r] = fwd ? b3[row] : 0.f;
            w4r[i * 4 + r] = W4[row];
        }

    // ---- layer-1 constants for OWN K-rows k = (2w+m)*16 + q*4 + j ----
    float A1v[8], w11v[8];
    {
        const float xs  = x[sbase + s];
        const float c0s = c0g[sbase + s];
        #pragma unroll
        for (int m = 0; m < 2; ++m)
            #pragma unroll
            for (int j = 0; j < 4; ++j) {
                const int k = (w * 2 + m) * 16 + q * 4 + j;
                w11v[m * 4 + j] = W1[k * 3 + 1];
                A1v[m * 4 + j]  = fmaf(xs, W1[k * 3 + 0],
                                       fmaf(c0s, W1[k * 3 + 2], b1[k]));
            }
    }

    float y = 0.0f;

    #pragma unroll 1
    for (int step = 0; step < 50; ++step) {
        // ---- layer 1 (own K-rows) -> split B1 chunks ----
        U4 B1h[2], B1l[2];
        #pragma unroll
        for (int m = 0; m < 2; ++m) {
            float v[4];
            #pragma unroll
            for (int j = 0; j < 4; ++j) {
                const float ww = w11v[m * 4 + j];
                const float z = fmaf(y, ww, A1v[m * 4 + j]);
                v[j] = fwd ? fmaxf(z, 0.f) : (z > 0.f ? ww : 0.f);
            }
            const unsigned h0 = pkrtz(v[0], v[1]);
            const unsigned h1 = pkrtz(v[2], v[3]);
            B1h[m].u[0] = h0; B1h[m].u[1] = h1;
            B1l[m].u[0] = pkrtz(lo0(h0, v[0]), lo1(h0, v[1]));
            B1l[m].u[1] = pkrtz(lo0(h1, v[2]), lo1(h1, v[3]));
        }
        // ---- layer 2: partial over own K-half, all 4 tiles ----
        f32x4 ZH[4], ZL[4];
        #pragma unroll
        for (int T = 0; T < 4; ++T) {
            f32x4 aH  = {0.f, 0.f, 0.f, 0.f};
            f32x4 aLa = {0.f, 0.f, 0.f, 0.f};
            f32x4 aLb = {0.f, 0.f, 0.f, 0.f};
            #pragma unroll
            for (int m = 0; m < 2; ++m) {
                aH  = __builtin_amdgcn_mfma_f32_16x16x16f16(W2h[T][m], B1h[m].v, aH, 0, 0, 0);
                aLa = __builtin_amdgcn_mfma_f32_16x16x16f16(W2h[T][m], B1l[m].v, aLa, 0, 0, 0);
                aLb = __builtin_amdgcn_mfma_f32_16x16x16f16(W2l[T][m], B1h[m].v, aLb, 0, 0, 0);
            }
            ZH[T] = aH; ZL[T] = aLa + aLb;
        }
        // write partials for the OTHER wave's tiles
        #pragma unroll
        for (int i = 0; i < 2; ++i) {
            const int To = 2 * (1 - w) + i;
            float4 pv;
            pv.x = fmaf(ZL[To][0], LOINV, ZH[To][0]);
            pv.y = fmaf(ZL[To][1], LOINV, ZH[To][1]);
            pv.z = fmaf(ZL[To][2], LOINV, ZH[To][2]);
            pv.w = fmaf(ZL[To][3], LOINV, ZH[To][3]);
            *(float4*)&pbuf2[To][lane][0] = pv;
        }
        __syncthreads();                               // barrier 1
        // combine own tiles + mask + split -> B2 chunks (own K-rows)
        float z2[8], rc2[8];
        #pragma unroll
        for (int i = 0; i < 2; ++i) {
            const int T = 2 * w + i;
            const float4 po = *(const float4*)&pbuf2[T][lane][0];
            z2[i * 4 + 0] = (fmaf(ZL[T][0], LOINV, ZH[T][0]) + po.x) + b2m[i * 4 + 0];
            z2[i * 4 + 1] = (fmaf(ZL[T][1], LOINV, ZH[T][1]) + po.y) + b2m[i * 4 + 1];
            z2[i * 4 + 2] = (fmaf(ZL[T][2], LOINV, ZH[T][2]) + po.z) + b2m[i * 4 + 2];
            z2[i * 4 + 3] = (fmaf(ZL[T][3], LOINV, ZH[T][3]) + po.w) + b2m[i * 4 + 3];
        }
        #pragma unroll
        for (int k = 0; k < 8; ++k) rc2[k] = __shfl_xor(z2[k], 8);
        U4 B2h[2], B2l[2];
        #pragma unroll
        for (int i = 0; i < 2; ++i) {
            float v[4];
            #pragma unroll
            for (int r = 0; r < 4; ++r) {
                const float z = z2[i * 4 + r];
                v[r] = fwd ? fmaxf(z, 0.f) : (rc2[i * 4 + r] > 0.f ? z : 0.f);
            }
            const unsigned h0 = pkrtz(v[0], v[1]);
            const unsigned h1 = pkrtz(v[2], v[3]);
            B2h[i].u[0] = h0; B2h[i].u[1] = h1;
            B2l[i].u[0] = pkrtz(lo0(h0, v[0]), lo1(h0, v[1]));
            B2l[i].u[1] = pkrtz(lo0(h1, v[2]), lo1(h1, v[3]));
        }
        // ---- layer 3: partial over own K-half ----
        #pragma unroll
        for (int T = 0; T < 4; ++T) {
            f32x4 aH  = {0.f, 0.f, 0.f, 0.f};
            f32x4 aLa = {0.f, 0.f, 0.f, 0.f};
            f32x4 aLb = {0.f, 0.f, 0.f, 0.f};
            #pragma unroll
            for (int m = 0; m < 2; ++m) {
                aH  = __builtin_amdgcn_mfma_f32_16x16x16f16(W3h[T][m], B2h[m].v, aH, 0, 0, 0);
                aLa = __builtin_amdgcn_mfma_f32_16x16x16f16(W3h[T][m], B2l[m].v, aLa, 0, 0, 0);
                aLb = __builtin_amdgcn_mfma_f32_16x16x16f16(W3l[T][m], B2h[m].v, aLb, 0, 0, 0);
            }
            ZH[T] = aH; ZL[T] = aLa + aLb;
        }
        #pragma unroll
        for (int i = 0; i < 2; ++i) {
            const int To = 2 * (1 - w) + i;
            float4 pv;
            pv.x = fmaf(ZL[To][0], LOINV, ZH[To][0]);
            pv.y = fmaf(ZL[To][1], LOINV, ZH[To][1]);
            pv.z = fmaf(ZL[To][2], LOINV, ZH[To][2]);
            pv.w = fmaf(ZL[To][3], LOINV, ZH[To][3]);
            *(float4*)&pbuf3[To][lane][0] = pv;
        }
        __syncthreads();                               // barrier 2
        // ---- layer 4 on own tiles: partial g ----
        float z3[8], rc3[8];
        #pragma unroll
        for (int i = 0; i < 2; ++i) {
            const int T = 2 * w + i;
            const float4 po = *(const float4*)&pbuf3[T][lane][0];
            z3[i * 4 + 0] = (fmaf(ZL[T][0], LOINV, ZH[T][0]) + po.x) + b3m[i * 4 + 0];
            z3[i * 4 + 1] = (fmaf(ZL[T][1], LOINV, ZH[T][1]) + po.y) + b3m[i * 4 + 1];
            z3[i * 4 + 2] = (fmaf(ZL[T][2], LOINV, ZH[T][2]) + po.z) + b3m[i * 4 + 2];
            z3[i * 4 + 3] = (fmaf(ZL[T][3], LOINV, ZH[T][3]) + po.w) + b3m[i * 4 + 3];
        }
        #pragma unroll
        for (int k = 0; k < 8; ++k) rc3[k] = __shfl_xor(z3[k], 8);
        float g = 0.f;
        #pragma unroll
        for (int k = 0; k < 8; ++k) {
            const float maskv = fwd ? z3[k] : rc3[k];   // z3 fwd (with bias)
            const float valv  = fwd ? rc3[k] : z3[k];   // dz3
            g = fmaf(w4r[k], (maskv > 0.f) ? valv : 0.f, g);
        }
        const float r1 = __shfl_xor(g, 16);
        const float r2 = __shfl_xor(g, 32);
        const float r3 = __shfl_xor(g, 48);
        const float gq = (g + r1) + (r2 + r3);          // own-tiles partial, q-summed
        if (lane < 16) gbuf[w][lane] = gq;
        __syncthreads();                               // barrier 3
        y -= 0.1f * (gbuf[0][cc] + gbuf[1][cc]);        // fixed order -> uniform y
    }
    if (w == 0 && lane < 8) out[sbase + lane] = y;
}

extern "C" void kernel_launch(void* const* d_in, const int* in_sizes, int n_in,
                              void* d_out, int out_size, void* d_ws, size_t ws_size,
                              hipStream_t stream) {
    const float* x  = (const float*)d_in[0];
    const float* c  = (const float*)d_in[1];
    const float* W1 = (const float*)d_in[2];
    const float* b1 = (const float*)d_in[3];
    const float* W2 = (const float*)d_in[4];
    const float* b2 = (const float*)d_in[5];
    const float* W3 = (const float*)d_in[6];
    const float* b3 = (const float*)d_in[7];
    const float* W4 = (const float*)d_in[8];
    // d_in[9] = b4: unused (only grad wrt y is needed, b4 drops out)
    float* c0  = (float*)d_ws;
    float* out = (float*)d_out;

    nn_kernel<<<BATCH / 8, 256, 0, stream>>>(c, c0);
    solve_kernel<<<BATCH / 8, 128, 0, stream>>>(x, c0, W1, b1, W2, b2, W3, b3, W4, out);
}

// Round 12
// 178.399 us; speedup vs baseline: 2.3490x; 2.3490x over previous
//
#include <hip/hip_runtime.h>

#define BATCH 8192
#define LOSC  2048.0f
#define LOINV (1.0f / 2048.0f)

typedef _Float16 f16x8 __attribute__((ext_vector_type(8)));
typedef __fp16   fp16x2 __attribute__((ext_vector_type(2)));
typedef float    f32x4 __attribute__((ext_vector_type(4)));

union PK2 { fp16x2 h; unsigned u; };
union U8  { f16x8 v; unsigned u[4]; };

__device__ __forceinline__ unsigned pkrtz(float a, float b) {
    PK2 p; p.h = __builtin_amdgcn_cvt_pkrtz(a, b); return p.u;
}
__device__ __forceinline__ float lo0(unsigned hp, float v) {
    PK2 p; p.u = hp; return (v - (float)p.h[0]) * LOSC;
}
__device__ __forceinline__ float lo1(unsigned hp, float v) {
    PK2 p; p.u = hp; return (v - (float)p.h[1]) * LOSC;
}

// ---------------------------------------------------------------------------
// Kernel 1: exact NN (CD=1). sqrt(fl(dx*dx)) == |dx| in fp32 -> fabsf;
// first-index argmin (strict < over ascending j), self excluded. ~5 us.
// ---------------------------------------------------------------------------
__global__ __launch_bounds__(256) void nn_kernel(const float* __restrict__ c,
                                                 float* __restrict__ c0) {
    __shared__ float cs[BATCH];
    const int t = threadIdx.x;
    {
        const float4* cg = (const float4*)c;
        float4* cl = (float4*)cs;
        for (int j = t; j < BATCH / 4; j += 256) cl[j] = cg[j];
    }
    __syncthreads();
    const int part = t & 31;
    const int i    = blockIdx.x * 8 + (t >> 5);
    const float ci = cs[i];
    const int sj0 = ((i & 3) == 0) ? (i >> 2) : -1;
    const int sj1 = ((i & 3) == 1) ? (i >> 2) : -1;
    const int sj2 = ((i & 3) == 2) ? (i >> 2) : -1;
    const int sj3 = ((i & 3) == 3) ? (i >> 2) : -1;
    const float4* cs4 = (const float4*)cs;
    float bd0 = 3e38f, bd1 = 3e38f, bd2 = 3e38f, bd3 = 3e38f;
    int   bj0 = 0,     bj1 = 0,     bj2 = 0,     bj3 = 0;
    #pragma unroll 4
    for (int tt = 0; tt < 64; ++tt) {
        const int jj = part + (tt << 5);
        const float4 v = cs4[jj];
        float d0 = fabsf(ci - v.x);
        float d1 = fabsf(ci - v.y);
        float d2 = fabsf(ci - v.z);
        float d3 = fabsf(ci - v.w);
        if (jj == sj0) d0 = 3e38f;
        if (jj == sj1) d1 = 3e38f;
        if (jj == sj2) d2 = 3e38f;
        if (jj == sj3) d3 = 3e38f;
        if (d0 < bd0) { bd0 = d0; bj0 = jj; }
        if (d1 < bd1) { bd1 = d1; bj1 = jj; }
        if (d2 < bd2) { bd2 = d2; bj2 = jj; }
        if (d3 < bd3) { bd3 = d3; bj3 = jj; }
    }
    float best = bd0; int bestj = bj0 * 4 + 0;
    { const int j1 = bj1 * 4 + 1; if (bd1 < best || (bd1 == best && j1 < bestj)) { best = bd1; bestj = j1; } }
    { const int j2 = bj2 * 4 + 2; if (bd2 < best || (bd2 == best && j2 < bestj)) { best = bd2; bestj = j2; } }
    { const int j3 = bj3 * 4 + 3; if (bd3 < best || (bd3 == best && j3 < bestj)) { best = bd3; bestj = j3; } }
    #pragma unroll
    for (int off = 1; off < 32; off <<= 1) {
        const float od = __shfl_xor(best, off);
        const int   oj = __shfl_xor(bestj, off);
        if (od < best || (od == best && oj < bestj)) { best = od; bestj = oj; }
    }
    if (part == 0) c0[i] = cs[bestj];
}

// ---------------------------------------------------------------------------
// Kernel 2 (v12): 8 samples/wave, 1024 blocks x 1 wave (hard occupancy cap;
// R6 duplication and R11 cooperation both lose). Split-f16 hi/lo via
// mfma_f32_16x16x32_f16 (K=32): HALF the MFMA count of the K=16 version
// (48 vs 96/step; K=16 and K=32 cost ~the same on the pipe). B1 is built
// directly in K=32 B layout (free); the one L2->L3 boundary uses the
// R4-verified 32-shfl C->B transform (C row=q*4+r -> B k=q*8+j lives in
// quads 2*(q&1)+{0,1}, tile select by q>>1). Layer 4 consumes C layout.
// R10's chain-split accumulators + 3-parallel-shfl reduce retained.
// ---------------------------------------------------------------------------
__global__ __launch_bounds__(64, 1) void solve_kernel(
    const float* __restrict__ x, const float* __restrict__ c0g,
    const float* __restrict__ W1, const float* __restrict__ b1,
    const float* __restrict__ W2, const float* __restrict__ b2,
    const float* __restrict__ W3, const float* __restrict__ b3,
    const float* __restrict__ W4, float* __restrict__ out)
{
    const int lane = threadIdx.x & 63;
    const int q  = lane >> 4;
    const int cc = lane & 15;
    const bool fwd = (cc < 8);
    const int s = cc & 7;
    const int sbase = blockIdx.x * 8;

    // ---- W2/W3 hi+lo fragments (K=32 A layout), all registers ----
    // A-frag (T,ch): lane holds W[(T*16+cc)][ch*32 + q*8 + j], j=0..7
    f16x8 W2h[4][2], W2l[4][2], W3h[4][2], W3l[4][2];
    #pragma unroll
    for (int T = 0; T < 4; ++T)
        #pragma unroll
        for (int ch = 0; ch < 2; ++ch) {
            const float* p2 = W2 + (T * 16 + cc) * 64 + ch * 32 + q * 8;
            const float* p3 = W3 + (T * 16 + cc) * 64 + ch * 32 + q * 8;
            const float4 a2 = *(const float4*)p2, b2v = *(const float4*)(p2 + 4);
            const float4 a3 = *(const float4*)p3, b3v = *(const float4*)(p3 + 4);
            U8 h, l;
            h.u[0] = pkrtz(a2.x, a2.y);   h.u[1] = pkrtz(a2.z, a2.w);
            h.u[2] = pkrtz(b2v.x, b2v.y); h.u[3] = pkrtz(b2v.z, b2v.w);
            l.u[0] = pkrtz(lo0(h.u[0], a2.x), lo1(h.u[0], a2.y));
            l.u[1] = pkrtz(lo0(h.u[1], a2.z), lo1(h.u[1], a2.w));
            l.u[2] = pkrtz(lo0(h.u[2], b2v.x), lo1(h.u[2], b2v.y));
            l.u[3] = pkrtz(lo0(h.u[3], b2v.z), lo1(h.u[3], b2v.w));
            W2h[T][ch] = h.v; W2l[T][ch] = l.v;
            h.u[0] = pkrtz(a3.x, a3.y);   h.u[1] = pkrtz(a3.z, a3.w);
            h.u[2] = pkrtz(b3v.x, b3v.y); h.u[3] = pkrtz(b3v.z, b3v.w);
            l.u[0] = pkrtz(lo0(h.u[0], a3.x), lo1(h.u[0], a3.y));
            l.u[1] = pkrtz(lo0(h.u[1], a3.z), lo1(h.u[1], a3.w));
            l.u[2] = pkrtz(lo0(h.u[2], b3v.x), lo1(h.u[2], b3v.y));
            l.u[3] = pkrtz(lo0(h.u[3], b3v.z), lo1(h.u[3], b3v.w));
            W3h[T][ch] = h.v; W3l[T][ch] = l.v;
        }

    // ---- pre-masked biases + W4, C-layout rows T*16 + q*4 + r ----
    float b2m[16], b3m[16], w4r[16];
    #pragma unroll
    for (int T = 0; T < 4; ++T)
        #pragma unroll
        for (int r = 0; r < 4; ++r) {
            const int row = T * 16 + q * 4 + r;
            b2m[T * 4 + r] = fwd ? b2[row] : 0.f;
            b3m[T * 4 + r] = fwd ? b3[row] : 0.f;
            w4r[T * 4 + r] = W4[row];
        }

    // ---- layer-1 constants: K=32 B rows k = ch*32 + q*8 + j ----
    float A1v[16], w11v[16];
    {
        const float xs  = x[sbase + s];
        const float c0s = c0g[sbase + s];
        #pragma unroll
        for (int ch = 0; ch < 2; ++ch)
            #pragma unroll
            for (int j = 0; j < 8; ++j) {
                const int k = ch * 32 + q * 8 + j;
                w11v[ch * 8 + j] = W1[k * 3 + 1];
                A1v[ch * 8 + j]  = fmaf(xs, W1[k * 3 + 0],
                                        fmaf(c0s, W1[k * 3 + 2], b1[k]));
            }
    }

    // transform source lanes (loop-invariant)
    const int srcA = ((q & 1) * 2) * 16 + cc;
    const int srcB = srcA + 16;
    const bool hiT = (q >> 1) != 0;

    float y = 0.0f;

    #pragma unroll 1
    for (int step = 0; step < 50; ++step) {
        // ---- layer 1 (fp32, registers) -> split B1 (K=32 layout, free) ----
        U8 B1h[2], B1l[2];
        #pragma unroll
        for (int ch = 0; ch < 2; ++ch) {
            float v[8];
            #pragma unroll
            for (int j = 0; j < 8; ++j) {
                const float w = w11v[ch * 8 + j];
                const float z = fmaf(y, w, A1v[ch * 8 + j]);
                v[j] = fwd ? fmaxf(z, 0.f) : (z > 0.f ? w : 0.f);
            }
            #pragma unroll
            for (int p = 0; p < 4; ++p) {
                const unsigned hp = pkrtz(v[2 * p], v[2 * p + 1]);
                B1h[ch].u[p] = hp;
                B1l[ch].u[p] = pkrtz(lo0(hp, v[2 * p]), lo1(hp, v[2 * p + 1]));
            }
        }
        // ---- layer 2: split MFMA (K=32 x 2 chunks), 3 chains per tile ----
        f32x4 ZH[4], ZL[4];
        #pragma unroll
        for (int T = 0; T < 4; ++T) {
            f32x4 aH;
            aH[0] = b2m[T * 4 + 0]; aH[1] = b2m[T * 4 + 1];
            aH[2] = b2m[T * 4 + 2]; aH[3] = b2m[T * 4 + 3];
            f32x4 aLa = {0.f, 0.f, 0.f, 0.f};
            f32x4 aLb = {0.f, 0.f, 0.f, 0.f};
            #pragma unroll
            for (int ch = 0; ch < 2; ++ch) {
                aH  = __builtin_amdgcn_mfma_f32_16x16x32_f16(W2h[T][ch], B1h[ch].v, aH, 0, 0, 0);
                aLa = __builtin_amdgcn_mfma_f32_16x16x32_f16(W2h[T][ch], B1l[ch].v, aLa, 0, 0, 0);
                aLb = __builtin_amdgcn_mfma_f32_16x16x32_f16(W2l[T][ch], B1h[ch].v, aLb, 0, 0, 0);
            }
            ZH[T] = aH; ZL[T] = aLa + aLb;
        }
        // ---- combine + batched mask shfls + select + split ----
        float z2[16], rc2[16];
        #pragma unroll
        for (int k = 0; k < 16; ++k)
            z2[k] = fmaf(ZL[k >> 2][k & 3], LOINV, ZH[k >> 2][k & 3]);
        #pragma unroll
        for (int k = 0; k < 16; ++k)
            rc2[k] = __shfl_xor(z2[k], 8);
        unsigned pkh[4][2], pkl[4][2];
        #pragma unroll
        for (int T = 0; T < 4; ++T) {
            float v[4];
            #pragma unroll
            for (int r = 0; r < 4; ++r) {
                const float z = z2[T * 4 + r];
                v[r] = fwd ? fmaxf(z, 0.f) : (rc2[T * 4 + r] > 0.f ? z : 0.f);
            }
            const unsigned h0 = pkrtz(v[0], v[1]);
            const unsigned h1 = pkrtz(v[2], v[3]);
            pkh[T][0] = h0; pkh[T][1] = h1;
            pkl[T][0] = pkrtz(lo0(h0, v[0]), lo1(h0, v[1]));
            pkl[T][1] = pkrtz(lo0(h1, v[2]), lo1(h1, v[3]));
        }
        // ---- C->B transform (R4-verified): 32 shfls + selects ----
        U8 B2h[2], B2l[2];
        #pragma unroll
        for (int ch = 0; ch < 2; ++ch)
            #pragma unroll
            for (int p = 0; p < 2; ++p) {
                const unsigned haL = (unsigned)__shfl((int)pkh[ch * 2][p],     srcA);
                const unsigned haH = (unsigned)__shfl((int)pkh[ch * 2 + 1][p], srcA);
                const unsigned hbL = (unsigned)__shfl((int)pkh[ch * 2][p],     srcB);
                const unsigned hbH = (unsigned)__shfl((int)pkh[ch * 2 + 1][p], srcB);
                const unsigned laL = (unsigned)__shfl((int)pkl[ch * 2][p],     srcA);
                const unsigned laH = (unsigned)__shfl((int)pkl[ch * 2 + 1][p], srcA);
                const unsigned lbL = (unsigned)__shfl((int)pkl[ch * 2][p],     srcB);
                const unsigned lbH = (unsigned)__shfl((int)pkl[ch * 2 + 1][p], srcB);
                B2h[ch].u[p]     = hiT ? haH : haL;
                B2h[ch].u[2 + p] = hiT ? hbH : hbL;
                B2l[ch].u[p]     = hiT ? laH : laL;
                B2l[ch].u[2 + p] = hiT ? lbH : lbL;
            }
        // ---- layer 3: split MFMA ----
        #pragma unroll
        for (int T = 0; T < 4; ++T) {
            f32x4 aH;
            aH[0] = b3m[T * 4 + 0]; aH[1] = b3m[T * 4 + 1];
            aH[2] = b3m[T * 4 + 2]; aH[3] = b3m[T * 4 + 3];
            f32x4 aLa = {0.f, 0.f, 0.f, 0.f};
            f32x4 aLb = {0.f, 0.f, 0.f, 0.f};
            #pragma unroll
            for (int ch = 0; ch < 2; ++ch) {
                aH  = __builtin_amdgcn_mfma_f32_16x16x32_f16(W3h[T][ch], B2h[ch].v, aH, 0, 0, 0);
                aLa = __builtin_amdgcn_mfma_f32_16x16x32_f16(W3h[T][ch], B2l[ch].v, aLa, 0, 0, 0);
                aLb = __builtin_amdgcn_mfma_f32_16x16x32_f16(W3l[T][ch], B2h[ch].v, aLb, 0, 0, 0);
            }
            ZH[T] = aH; ZL[T] = aLa + aLb;
        }
        // ---- layer 4 (fp32): batched shfls; g = W4 . (1[z3>0] * dz3) ----
        float z3[16], rc3[16];
        #pragma unroll
        for (int k = 0; k < 16; ++k)
            z3[k] = fmaf(ZL[k >> 2][k & 3], LOINV, ZH[k >> 2][k & 3]);
        #pragma unroll
        for (int k = 0; k < 16; ++k)
            rc3[k] = __shfl_xor(z3[k], 8);
        float g = 0.f;
        #pragma unroll
        for (int k = 0; k < 16; ++k) {
            const float maskv = fwd ? z3[k] : rc3[k];   // z3 fwd (with bias)
            const float valv  = fwd ? rc3[k] : z3[k];   // dz3
            g = fmaf(w4r[k], (maskv > 0.f) ? valv : 0.f, g);
        }
        const float r1 = __shfl_xor(g, 16);
        const float r2 = __shfl_xor(g, 32);
        const float r3 = __shfl_xor(g, 48);
        y -= 0.1f * ((g + r1) + (r2 + r3));
    }
    if (lane < 8) out[sbase + lane] = y;
}

extern "C" void kernel_launch(void* const* d_in, const int* in_sizes, int n_in,
                              void* d_out, int out_size, void* d_ws, size_t ws_size,
                              hipStream_t stream) {
    const float* x  = (const float*)d_in[0];
    const float* c  = (const float*)d_in[1];
    const float* W1 = (const float*)d_in[2];
    const float* b1 = (const float*)d_in[3];
    const float* W2 = (const float*)d_in[4];
    const float* b2 = (const float*)d_in[5];
    const float* W3 = (const float*)d_in[6];
    const float* b3 = (const float*)d_in[7];
    const float* W4 = (const float*)d_in[8];
    // d_in[9] = b4: unused (only grad wrt y is needed, b4 drops out)
    float* c0  = (float*)d_ws;
    float* out = (float*)d_out;

    nn_kernel<<<BATCH / 8, 256, 0, stream>>>(c, c0);
    solve_kernel<<<BATCH / 8, 64, 0, stream>>>(x, c0, W1, b1, W2, b2, W3, b3, W4, out);
}